// Round 7
// baseline (726.920 us; speedup 1.0000x reference)
//
#include <hip/hip_runtime.h>

#define NB 2048
#define NT 128

typedef float v2f __attribute__((ext_vector_type(2)));

static __device__ __forceinline__ v2f pkfma(v2f a, v2f b, v2f c) {
#if __has_builtin(__builtin_elementwise_fma)
    return __builtin_elementwise_fma(a, b, c);
#else
    v2f r; r.x = fmaf(a.x, b.x, c.x); r.y = fmaf(a.y, b.y, c.y); return r;
#endif
}
static __device__ __forceinline__ v2f mkv2(float x, float y) { v2f r; r.x = x; r.y = y; return r; }

// DPP lane shuffle (VALU pipe, not DS). CTRL: quad_perm/mirror encodings.
template<int CTRL>
static __device__ __forceinline__ float dppf(float v) {
    return __int_as_float(__builtin_amdgcn_update_dpp(
        __float_as_int(v), __float_as_int(v), CTRL, 0xF, 0xF, false));
}
#define DPP_QP1 0xB1   // quad_perm [1,0,3,2] : lane ^ 1
#define DPP_QP2 0x4E   // quad_perm [2,3,0,1] : lane ^ 2
#define DPP_HM  0x141  // row_half_mirror     : lane ^ 7 (within 8)
#define DPP_MIR 0x140  // row_mirror          : lane ^ 15 (within 16)

// ---------------------------------------------------------------------------
// Kernel 1: action-latent MLP  (B*T, 8) -> relu(64) -> (B*T, 16), into d_ws
// ---------------------------------------------------------------------------
__global__ __launch_bounds__(256, 4) void acl_kernel(
    const float* __restrict__ acs, const float* __restrict__ acW0,
    const float* __restrict__ acb0, const float* __restrict__ acW1,
    const float* __restrict__ acb1, float* __restrict__ aclout)
{
    __shared__ float sW0[64 * 8];
    __shared__ float sW1[16 * 64];
    __shared__ float sB0[64];
    __shared__ float sB1[16];
    const int tid = threadIdx.x;
    for (int i = tid; i < 64 * 8; i += 256) sW0[i] = acW0[i];
    for (int i = tid; i < 16 * 64; i += 256) sW1[i] = acW1[i];
    if (tid < 64) sB0[tid] = acb0[tid];
    if (tid < 16) sB1[tid] = acb1[tid];
    __syncthreads();

    const int row = blockIdx.x * 256 + tid;
    const float4 x0 = *(const float4*)&acs[row * 8];
    const float4 x1 = *(const float4*)&acs[row * 8 + 4];

    float o[16];
    #pragma unroll
    for (int m = 0; m < 16; ++m) o[m] = sB1[m];

    #pragma unroll
    for (int jc = 0; jc < 16; ++jc) {
        float hq[4];
        #pragma unroll
        for (int u = 0; u < 4; ++u) {
            const int j = jc * 4 + u;
            const float4 wa = *(const float4*)&sW0[j * 8];
            const float4 wb = *(const float4*)&sW0[j * 8 + 4];
            float hv = sB0[j];
            hv = fmaf(x0.x, wa.x, hv); hv = fmaf(x0.y, wa.y, hv);
            hv = fmaf(x0.z, wa.z, hv); hv = fmaf(x0.w, wa.w, hv);
            hv = fmaf(x1.x, wb.x, hv); hv = fmaf(x1.y, wb.y, hv);
            hv = fmaf(x1.z, wb.z, hv); hv = fmaf(x1.w, wb.w, hv);
            hq[u] = fmaxf(hv, 0.f);
        }
        #pragma unroll
        for (int m = 0; m < 16; ++m) {
            const float4 wv = *(const float4*)&sW1[m * 64 + jc * 4];
            o[m] = fmaf(hq[0], wv.x, o[m]);
            o[m] = fmaf(hq[1], wv.y, o[m]);
            o[m] = fmaf(hq[2], wv.z, o[m]);
            o[m] = fmaf(hq[3], wv.w, o[m]);
        }
    }
    float4* op = (float4*)&aclout[row * 16];
    op[0] = make_float4(o[0],  o[1],  o[2],  o[3]);
    op[1] = make_float4(o[4],  o[5],  o[6],  o[7]);
    op[2] = make_float4(o[8],  o[9],  o[10], o[11]);
    op[3] = make_float4(o[12], o[13], o[14], o[15]);
}

// ---------------------------------------------------------------------------
// Kernel 2 v8: LDS-free inner loop.
//  - ystar_j = W0y.y maintained per-lane: ystar += hh*gproj(hacc); a1 = ystar
//    + b0 + aclPart needs no broadcast.
//  - gproj: gather 16 row-group h values by a 15-mov DPP doubling tree
//    (xor set {1,2,7,15}); quarter-dots for rows {j, j^16, j^32, j^48} with
//    load-time-permuted M columns; combine via 2x shfl_xor(16) + shfl_xor(32).
//    DS ops/gproj: 10 -> 3.
//  - y materialized once per interval from haccSum (same algebra, reordered
//    rounding), stored to out cols 0..31; dec_kernel decodes in place.
// ---------------------------------------------------------------------------
__global__ __launch_bounds__(256, 2) void ode_kernel(
    const float* __restrict__ encW0, const float* __restrict__ encb0,
    const float* __restrict__ encW1, const float* __restrict__ encb1,
    const float* __restrict__ dynW0, const float* __restrict__ dynb0,
    const float* __restrict__ dynW1, const float* __restrict__ dynb1,
    const float* __restrict__ ob,    const float* __restrict__ times,
    const float* __restrict__ aclws, float* __restrict__ yio)
{
    __shared__ float sEncW0T[64 * 64];   // [k][j]
    __shared__ float sEncW1T[64 * 32];   // [j][m]
    __shared__ float sW0s[64 * 32];      // W0y rows: [j][m]
    __shared__ float sW1T[64 * 32];      // W1 cols:  [j'][m]
    __shared__ float sM[64 * 64];        // M[j][j'] = sum_m W0y[j][m] W1[m][j']
    __shared__ float sEncB0[64], sEncB1[32], sB1d[32];
    __shared__ float xbuf[4][64];
    __shared__ float hbuf[4][64];
    __shared__ float tbuf[4][NT];

    const int tid = threadIdx.x;
    for (int i = tid; i < 64 * 64; i += 256) { int r = i >> 6, c = i & 63; sEncW0T[c * 64 + r] = encW0[i]; }
    for (int i = tid; i < 32 * 64; i += 256) { int r = i >> 6, c = i & 63; sEncW1T[c * 32 + r] = encW1[i]; }
    for (int i = tid; i < 64 * 32; i += 256) { int j = i >> 5, mm = i & 31; sW0s[i] = dynW0[j * 48 + mm]; }
    for (int i = tid; i < 64 * 32; i += 256) { int c = i >> 5, mm = i & 31; sW1T[i] = dynW1[mm * 64 + c]; }
    if (tid < 64) { sEncB0[tid] = encb0[tid]; }
    if (tid < 32) { sEncB1[tid] = encb1[tid]; sB1d[tid] = dynb1[tid]; }
    __syncthreads();

    // ---- compute sM cooperatively: thread t -> row j = t>>2, 16 cols
    {
        const int j  = tid >> 2;
        const int cg = (tid & 3) * 16;
        float4 wr[8];
        #pragma unroll
        for (int q = 0; q < 8; ++q) wr[q] = *(const float4*)&sW0s[j * 32 + q * 4];
        #pragma unroll 2
        for (int k = 0; k < 16; ++k) {
            const int c = cg + k;
            v2f s0 = mkv2(0.f, 0.f), s1 = mkv2(0.f, 0.f);
            #pragma unroll
            for (int q = 0; q < 8; ++q) {
                const float4 t4 = *(const float4*)&sW1T[c * 32 + q * 4];
                s0 = pkfma(mkv2(t4.x, t4.y), mkv2(wr[q].x, wr[q].y), s0);
                s1 = pkfma(mkv2(t4.z, t4.w), mkv2(wr[q].z, wr[q].w), s1);
            }
            sM[j * 64 + c] = (s0.x + s1.x) + (s0.y + s1.y);
        }
    }
    __syncthreads();

    const int w    = tid >> 6;
    const int lane = tid & 63;
    const int bu   = __builtin_amdgcn_readfirstlane(blockIdx.x * 4 + w);
    const int m    = lane & 31;
    const int H    = lane & 32;
    const int rb   = lane & 48;          // 16-lane row-group base
    const int off  = lane & 15;

    float* __restrict__ xb = xbuf[w];
    float* __restrict__ hb = hbuf[w];

    // gather column order (must match the DPP tree below): value u of reg q
    // holds h[rb | (off ^ XT[q][u])]
    constexpr int XT[8][2] = {{0,1},{2,3},{7,6},{5,4},{15,14},{13,12},{8,9},{10,11}};

    // M quarter-row weights for rows j, j^16, j^32, j^48, gather-permuted
    v2f WM0[8], WM1[8], WM2[8], WM3[8];
    #pragma unroll
    for (int q = 0; q < 8; ++q) {
        const int c0 = rb | (off ^ XT[q][0]);
        const int c1 = rb | (off ^ XT[q][1]);
        WM0[q] = mkv2(sM[lane * 64 + c0],        sM[lane * 64 + c1]);
        WM1[q] = mkv2(sM[(lane ^ 16) * 64 + c0], sM[(lane ^ 16) * 64 + c1]);
        WM2[q] = mkv2(sM[(lane ^ 32) * 64 + c0], sM[(lane ^ 32) * 64 + c1]);
        WM3[q] = mkv2(sM[(lane ^ 48) * 64 + c0], sM[(lane ^ 48) * 64 + c1]);
    }
    // W1 quarter-row weights for rows m, m^16 (y-update), gather-permuted
    v2f V10[8], V11[8];
    #pragma unroll
    for (int q = 0; q < 8; ++q) {
        const int c0 = rb | (off ^ XT[q][0]);
        const int c1 = rb | (off ^ XT[q][1]);
        V10[q] = mkv2(dynW1[m * 64 + c0],        dynW1[m * 64 + c1]);
        V11[q] = mkv2(dynW1[(m ^ 16) * 64 + c0], dynW1[(m ^ 16) * 64 + c1]);
    }
    // acl columns of W0 row j
    float wa[16];
    #pragma unroll
    for (int q = 0; q < 4; ++q) *(float4*)&wa[q * 4] = *(const float4*)&dynW0[lane * 48 + 32 + q * 4];
    const float b0r = dynb0[lane];
    const float b1r = dynb1[m];

    tbuf[w][lane]      = times[bu * NT + lane];
    tbuf[w][64 + lane] = times[bu * NT + 64 + lane];
    __builtin_amdgcn_wave_barrier();

    // DPP doubling gather: 15 movs -> 16 row-group h values (order = XT)
    auto gather = [&](float h, v2f* G) {
        G[0] = mkv2(h,                     dppf<DPP_QP1>(h));
        G[1] = mkv2(dppf<DPP_QP2>(G[0].x), dppf<DPP_QP2>(G[0].y));
        G[2] = mkv2(dppf<DPP_HM >(G[0].x), dppf<DPP_HM >(G[0].y));
        G[3] = mkv2(dppf<DPP_HM >(G[1].x), dppf<DPP_HM >(G[1].y));
        G[4] = mkv2(dppf<DPP_MIR>(G[0].x), dppf<DPP_MIR>(G[0].y));
        G[5] = mkv2(dppf<DPP_MIR>(G[1].x), dppf<DPP_MIR>(G[1].y));
        G[6] = mkv2(dppf<DPP_MIR>(G[2].x), dppf<DPP_MIR>(G[2].y));
        G[7] = mkv2(dppf<DPP_MIR>(G[3].x), dppf<DPP_MIR>(G[3].y));
    };

    // g_j = M[j,:].h + vj via quarter-dots + 3 cross-lane combines
    auto gproj = [&](float h, float vjv) -> float {
        v2f G[8];
        gather(h, G);
        v2f P0 = mkv2(0.f, 0.f), P1 = mkv2(0.f, 0.f);
        v2f P2 = mkv2(0.f, 0.f), P3 = mkv2(0.f, 0.f);
        #pragma unroll
        for (int q = 0; q < 8; ++q) {
            P0 = pkfma(G[q], WM0[q], P0);
            P1 = pkfma(G[q], WM1[q], P1);
            P2 = pkfma(G[q], WM2[q], P2);
            P3 = pkfma(G[q], WM3[q], P3);
        }
        const float p0 = P0.x + P0.y, p1 = P1.x + P1.y;
        const float p2 = P2.x + P2.y, p3 = P3.x + P3.y;
        const float u  = p0 + __shfl_xor(p1, 16, 64);
        const float vv = p2 + __shfl_xor(p3, 16, 64);
        return u + __shfl_xor(vv, 32, 64) + vjv;
    };

    // ---- encoder: ob(64) -> relu(64) -> y(32), y replicated in both halves
    float y;
    {
        xb[lane] = ob[bu * 64 + lane];
        __builtin_amdgcn_wave_barrier();
        float4 xv[16];
        #pragma unroll
        for (int q = 0; q < 16; ++q) xv[q] = *(const float4*)&xb[q * 4];
        float a0 = sEncB0[lane], a1 = 0.f, a2 = 0.f, a3 = 0.f;
        #pragma unroll
        for (int q = 0; q < 16; ++q) {
            a0 = fmaf(xv[q].x, sEncW0T[(q * 4 + 0) * 64 + lane], a0);
            a1 = fmaf(xv[q].y, sEncW0T[(q * 4 + 1) * 64 + lane], a1);
            a2 = fmaf(xv[q].z, sEncW0T[(q * 4 + 2) * 64 + lane], a2);
            a3 = fmaf(xv[q].w, sEncW0T[(q * 4 + 3) * 64 + lane], a3);
        }
        const float hj = fmaxf((a0 + a1) + (a2 + a3), 0.f);
        hb[lane] = hj;
        __builtin_amdgcn_wave_barrier();
        float4 hv[8];
        #pragma unroll
        for (int q = 0; q < 8; ++q) hv[q] = *(const float4*)&hb[H + q * 4];
        float c0 = 0.f, c1 = 0.f, c2 = 0.f, c3 = 0.f;
        #pragma unroll
        for (int q = 0; q < 8; ++q) {
            c0 = fmaf(hv[q].x, sEncW1T[(H + q * 4 + 0) * 32 + m], c0);
            c1 = fmaf(hv[q].y, sEncW1T[(H + q * 4 + 1) * 32 + m], c1);
            c2 = fmaf(hv[q].z, sEncW1T[(H + q * 4 + 2) * 32 + m], c2);
            c3 = fmaf(hv[q].w, sEncW1T[(H + q * 4 + 3) * 32 + m], c3);
        }
        float part = (c0 + c1) + (c2 + c3);
        part += __shfl_xor(part, 32, 64);
        y = part + sEncB1[m];
    }

    // ---- init ystar = W0y[j,:].y and vj = W0y[j,:].b1 (one pass, one-time)
    float ystar = 0.f, vj = 0.f;
    {
        __builtin_amdgcn_wave_barrier();
        xb[m] = y;                        // both pair-lanes: same addr, same data
        __builtin_amdgcn_wave_barrier();
        #pragma unroll
        for (int q = 0; q < 8; ++q) {
            const float4 wv = *(const float4*)&dynW0[lane * 48 + q * 4];
            const float4 xv = *(const float4*)&xb[q * 4];
            ystar = fmaf(wv.x, xv.x, ystar); ystar = fmaf(wv.y, xv.y, ystar);
            ystar = fmaf(wv.z, xv.z, ystar); ystar = fmaf(wv.w, xv.w, ystar);
            vj = fmaf(wv.x, sB1d[q * 4 + 0], vj); vj = fmaf(wv.y, sB1d[q * 4 + 1], vj);
            vj = fmaf(wv.z, sB1d[q * 4 + 2], vj); vj = fmaf(wv.w, sB1d[q * 4 + 3], vj);
        }
    }

    // per-lane acl partial: aclPart = sum_k w0[lane][32+k] * acl[k]
    auto acl_part = [&](const float* __restrict__ ap) -> float {
        float ar[16];
        #pragma unroll
        for (int q = 0; q < 4; ++q) *(float4*)&ar[q * 4] = *(const float4*)&ap[q * 4];
        const v2f* a2 = (const v2f*)ar;
        const v2f* wq = (const v2f*)wa;
        v2f s0 = mkv2(0.f, 0.f), s1 = mkv2(0.f, 0.f);
        #pragma unroll
        for (int q = 0; q < 8; q += 2) {
            s0 = pkfma(a2[q],     wq[q],     s0);
            s1 = pkfma(a2[q + 1], wq[q + 1], s1);
        }
        const v2f s = s0 + s1;
        return s.x + s.y;
    };

    auto store_y = [&](float yv, int t) {
        if (lane < 32) yio[(size_t)(bu * NT + t) * 64 + lane] = yv;
    };

    float aclPartC = acl_part(aclws + (size_t)(bu * NT) * 16);
    store_y(y, 0);

    for (int i = 0; i < NT - 1; ++i) {
        const float t0v = tbuf[w][i];
        const float t1v = tbuf[w][i + 1];
        const float hh  = (t1v - t0v) * 0.5f;                       // /K, K=2
        const float aclPartN = acl_part(aclws + (size_t)(bu * NT + i + 1) * 16);
        float haccS = 0.f;

        #pragma unroll 1
        for (int sub = 0; sub < 2; ++sub) {
            const float tsub  = t0v + (float)sub * hh;
            // stage-6 time fl(tsub+hh): matches reference searchsorted('right')
            const bool  swap6 = (tsub + hh >= t1v);

            const float a1v = ystar + b0r + aclPartC;

            const float h1 = fmaxf(a1v, 0.f);
            const float g1 = hh * gproj(h1, vj);
            const float h2 = fmaxf(fmaf(0.2f, g1, a1v), 0.f);
            const float g2 = hh * gproj(h2, vj);
            const float h3 = fmaxf(fmaf(0.075f, g1, fmaf(0.225f, g2, a1v)), 0.f);
            const float g3 = hh * gproj(h3, vj);
            const float h4 = fmaxf(
                fmaf((float)(44.0/45.0), g1,
                fmaf((float)(-56.0/15.0), g2,
                fmaf((float)(32.0/9.0), g3, a1v))), 0.f);
            const float g4 = hh * gproj(h4, vj);
            const float h5 = fmaxf(
                fmaf((float)(19372.0/6561.0), g1,
                fmaf((float)(-25360.0/2187.0), g2,
                fmaf((float)(64448.0/6561.0), g3,
                fmaf((float)(-212.0/729.0), g4, a1v)))), 0.f);
            const float g5 = hh * gproj(h5, vj);
            float a6v =
                fmaf((float)(9017.0/3168.0), g1,
                fmaf((float)(-355.0/33.0), g2,
                fmaf((float)(46732.0/5247.0), g3,
                fmaf((float)(49.0/176.0), g4,
                fmaf((float)(-5103.0/18656.0), g5, a1v)))));
            a6v += swap6 ? (aclPartN - aclPartC) : 0.f;
            const float h6 = fmaxf(a6v, 0.f);

            // hacc = sum_s B_s h_s  (B2 = 0)
            float ha = (float)(35.0/384.0) * h1;
            ha = fmaf((float)(500.0/1113.0),   h3, ha);
            ha = fmaf((float)(125.0/192.0),    h4, ha);
            ha = fmaf((float)(-2187.0/6784.0), h5, ha);
            ha = fmaf((float)(11.0/84.0),      h6, ha);

            // ystar advance: W0y.y_next = W0y.y + hh*(M.hacc + v)
            const float gacc = gproj(ha, vj);
            ystar = fmaf(hh, gacc, ystar);
            haccS += ha;
        }

        // y materialization, once per interval:
        // y += hh*(W1.haccSum + 2*b1)
        {
            v2f G[8];
            gather(haccS, G);
            v2f P0 = mkv2(0.f, 0.f), P1 = mkv2(0.f, 0.f);
            #pragma unroll
            for (int q = 0; q < 8; ++q) {
                P0 = pkfma(G[q], V10[q], P0);
                P1 = pkfma(G[q], V11[q], P1);
            }
            const float p0 = P0.x + P0.y, p1 = P1.x + P1.y;
            const float u  = p0 + __shfl_xor(p1, 16, 64);
            const float gf = u + __shfl_xor(u, 32, 64);
            y = fmaf(hh, gf + 2.f * b1r, y);
        }
        aclPartC = aclPartN;
        store_y(y, i + 1);
    }
}

// ---------------------------------------------------------------------------
// Kernel 3: decoder, one thread per (b,t) row, IN PLACE on out. Packed fp32.
// ---------------------------------------------------------------------------
__global__ __launch_bounds__(256, 2) void dec_kernel(
    const float* __restrict__ decW0, const float* __restrict__ decb0,
    const float* __restrict__ decW1, const float* __restrict__ decb1,
    float* __restrict__ yio)
{
    __shared__ float sW0[64 * 32];   // [j][k] as stored
    __shared__ float sW1T[64 * 64];  // [j][n]
    __shared__ float sB0[64];
    __shared__ float sB1[64];
    const int tid = threadIdx.x;
    for (int i = tid; i < 64 * 32; i += 256) sW0[i] = decW0[i];
    for (int i = tid; i < 64 * 64; i += 256) { int n = i >> 6, j = i & 63; sW1T[j * 64 + n] = decW1[i]; }
    if (tid < 64) { sB0[tid] = decb0[tid]; sB1[tid] = decb1[tid]; }
    __syncthreads();

    const size_t row = (size_t)blockIdx.x * 256 + tid;
    float* rp = &yio[row * 64];

    float xr[32];
    #pragma unroll
    for (int q = 0; q < 8; ++q) *(float4*)&xr[q * 4] = *(const float4*)&rp[q * 4];

    v2f o2[32];
    #pragma unroll
    for (int n = 0; n < 32; ++n) o2[n] = mkv2(sB1[2 * n], sB1[2 * n + 1]);

    #pragma unroll 4
    for (int j = 0; j < 64; ++j) {
        v2f a0 = mkv2(sB0[j], 0.f), a1 = mkv2(0.f, 0.f);
        #pragma unroll
        for (int q = 0; q < 8; ++q) {
            const float4 wv = *(const float4*)&sW0[j * 32 + q * 4];
            a0 = pkfma(*(const v2f*)&xr[q * 4],     mkv2(wv.x, wv.y), a0);
            a1 = pkfma(*(const v2f*)&xr[q * 4 + 2], mkv2(wv.z, wv.w), a1);
        }
        const float hj = fmaxf((a0.x + a1.x) + (a0.y + a1.y), 0.f);
        const v2f h2 = mkv2(hj, hj);
        #pragma unroll
        for (int q = 0; q < 16; ++q) {
            const float4 wv = *(const float4*)&sW1T[j * 64 + q * 4];
            o2[2 * q]     = pkfma(h2, mkv2(wv.x, wv.y), o2[2 * q]);
            o2[2 * q + 1] = pkfma(h2, mkv2(wv.z, wv.w), o2[2 * q + 1]);
        }
    }

    #pragma unroll
    for (int q = 0; q < 16; ++q)
        *(float4*)&rp[q * 4] = make_float4(o2[2 * q].x, o2[2 * q].y,
                                           o2[2 * q + 1].x, o2[2 * q + 1].y);
}

extern "C" void kernel_launch(void* const* d_in, const int* in_sizes, int n_in,
                              void* d_out, int out_size, void* d_ws, size_t ws_size,
                              hipStream_t stream)
{
    const float* encW0 = (const float*)d_in[0];
    const float* encb0 = (const float*)d_in[1];
    const float* encW1 = (const float*)d_in[2];
    const float* encb1 = (const float*)d_in[3];
    const float* acW0  = (const float*)d_in[4];
    const float* acb0  = (const float*)d_in[5];
    const float* acW1  = (const float*)d_in[6];
    const float* acb1  = (const float*)d_in[7];
    const float* dynW0 = (const float*)d_in[8];
    const float* dynb0 = (const float*)d_in[9];
    const float* dynW1 = (const float*)d_in[10];
    const float* dynb1 = (const float*)d_in[11];
    const float* decW0 = (const float*)d_in[12];
    const float* decb0 = (const float*)d_in[13];
    const float* decW1 = (const float*)d_in[14];
    const float* decb1 = (const float*)d_in[15];
    const float* ob    = (const float*)d_in[16];
    const float* acs   = (const float*)d_in[17];
    const float* times = (const float*)d_in[18];
    float* out = (float*)d_out;
    float* acl = (float*)d_ws;   // NB*NT*16 floats = 16.8 MB scratch

    acl_kernel<<<(NB * NT) / 256, 256, 0, stream>>>(acs, acW0, acb0, acW1, acb1, acl);
    ode_kernel<<<NB / 4, 256, 0, stream>>>(encW0, encb0, encW1, encb1,
                                           dynW0, dynb0, dynW1, dynb1,
                                           ob, times, acl, out);
    dec_kernel<<<(NB * NT) / 256, 256, 0, stream>>>(decW0, decb0, decW1, decb1, out);
}

// Round 8
// 622.818 us; speedup vs baseline: 1.1671x; 1.1671x over previous
//
#include <hip/hip_runtime.h>

#define NB 2048
#define NT 128

typedef float v2f __attribute__((ext_vector_type(2)));

static __device__ __forceinline__ v2f pkfma(v2f a, v2f b, v2f c) {
#if __has_builtin(__builtin_elementwise_fma)
    return __builtin_elementwise_fma(a, b, c);
#else
    v2f r; r.x = fmaf(a.x, b.x, c.x); r.y = fmaf(a.y, b.y, c.y); return r;
#endif
}
static __device__ __forceinline__ v2f mkv2(float x, float y) { v2f r; r.x = x; r.y = y; return r; }

// ---------------------------------------------------------------------------
// Kernel 1: action-latent MLP  (B*T, 8) -> relu(64) -> (B*T, 16), into d_ws
// ---------------------------------------------------------------------------
__global__ __launch_bounds__(256, 4) void acl_kernel(
    const float* __restrict__ acs, const float* __restrict__ acW0,
    const float* __restrict__ acb0, const float* __restrict__ acW1,
    const float* __restrict__ acb1, float* __restrict__ aclout)
{
    __shared__ float sW0[64 * 8];
    __shared__ float sW1[16 * 64];
    __shared__ float sB0[64];
    __shared__ float sB1[16];
    const int tid = threadIdx.x;
    for (int i = tid; i < 64 * 8; i += 256) sW0[i] = acW0[i];
    for (int i = tid; i < 16 * 64; i += 256) sW1[i] = acW1[i];
    if (tid < 64) sB0[tid] = acb0[tid];
    if (tid < 16) sB1[tid] = acb1[tid];
    __syncthreads();

    const int row = blockIdx.x * 256 + tid;
    const float4 x0 = *(const float4*)&acs[row * 8];
    const float4 x1 = *(const float4*)&acs[row * 8 + 4];

    float o[16];
    #pragma unroll
    for (int m = 0; m < 16; ++m) o[m] = sB1[m];

    #pragma unroll
    for (int jc = 0; jc < 16; ++jc) {
        float hq[4];
        #pragma unroll
        for (int u = 0; u < 4; ++u) {
            const int j = jc * 4 + u;
            const float4 wa = *(const float4*)&sW0[j * 8];
            const float4 wb = *(const float4*)&sW0[j * 8 + 4];
            float hv = sB0[j];
            hv = fmaf(x0.x, wa.x, hv); hv = fmaf(x0.y, wa.y, hv);
            hv = fmaf(x0.z, wa.z, hv); hv = fmaf(x0.w, wa.w, hv);
            hv = fmaf(x1.x, wb.x, hv); hv = fmaf(x1.y, wb.y, hv);
            hv = fmaf(x1.z, wb.z, hv); hv = fmaf(x1.w, wb.w, hv);
            hq[u] = fmaxf(hv, 0.f);
        }
        #pragma unroll
        for (int m = 0; m < 16; ++m) {
            const float4 wv = *(const float4*)&sW1[m * 64 + jc * 4];
            o[m] = fmaf(hq[0], wv.x, o[m]);
            o[m] = fmaf(hq[1], wv.y, o[m]);
            o[m] = fmaf(hq[2], wv.z, o[m]);
            o[m] = fmaf(hq[3], wv.w, o[m]);
        }
    }
    float4* op = (float4*)&aclout[row * 16];
    op[0] = make_float4(o[0],  o[1],  o[2],  o[3]);
    op[1] = make_float4(o[4],  o[5],  o[6],  o[7]);
    op[2] = make_float4(o[8],  o[9],  o[10], o[11]);
    op[3] = make_float4(o[12], o[13], o[14], o[15]);
}

// ---------------------------------------------------------------------------
// Kernel 2 v9: v7 structure (pre-activation recurrence, 474 µs anchor) with
// QUARTER-SPLIT LDS dots: each lane computes 4 rows {j, j^16, j^32, j^48}
// over a 16-col quarter (rb = lane&48), reading 4xb128 instead of 8, then
// combines via 3x shfl_xor (combine pattern verified in v8).
//   per substep: b128 reads 56 -> 26, writes 7 (unchanged), shfls 6 -> 20.
// VALU unchanged (no DPP tree); register footprint = v7's (144 wt floats).
// ---------------------------------------------------------------------------
__global__ __launch_bounds__(256, 2) void ode_kernel(
    const float* __restrict__ encW0, const float* __restrict__ encb0,
    const float* __restrict__ encW1, const float* __restrict__ encb1,
    const float* __restrict__ dynW0, const float* __restrict__ dynb0,
    const float* __restrict__ dynW1, const float* __restrict__ dynb1,
    const float* __restrict__ ob,    const float* __restrict__ times,
    const float* __restrict__ aclws, float* __restrict__ yio)
{
    __shared__ float sEncW0T[64 * 64];   // [k][j]
    __shared__ float sEncW1T[64 * 32];   // [j][m]
    __shared__ float sW0s[64 * 32];      // W0y rows: [j][m]
    __shared__ float sW1T[64 * 32];      // W1 cols:  [j'][m]
    __shared__ float sM[64 * 64];        // M[j][j'] = sum_m W0y[j][m] W1[m][j']
    __shared__ float sEncB0[64], sEncB1[32], sB1d[32];
    __shared__ float xbuf[4][64];
    __shared__ float hbuf[4][64];
    __shared__ float tbuf[4][NT];

    const int tid = threadIdx.x;
    for (int i = tid; i < 64 * 64; i += 256) { int r = i >> 6, c = i & 63; sEncW0T[c * 64 + r] = encW0[i]; }
    for (int i = tid; i < 32 * 64; i += 256) { int r = i >> 6, c = i & 63; sEncW1T[c * 32 + r] = encW1[i]; }
    for (int i = tid; i < 64 * 32; i += 256) { int j = i >> 5, mm = i & 31; sW0s[i] = dynW0[j * 48 + mm]; }
    for (int i = tid; i < 64 * 32; i += 256) { int c = i >> 5, mm = i & 31; sW1T[i] = dynW1[mm * 64 + c]; }
    if (tid < 64) { sEncB0[tid] = encb0[tid]; }
    if (tid < 32) { sEncB1[tid] = encb1[tid]; sB1d[tid] = dynb1[tid]; }
    __syncthreads();

    // ---- compute sM cooperatively: thread t -> row j = t>>2, 16 cols
    {
        const int j  = tid >> 2;
        const int cg = (tid & 3) * 16;
        float4 wr[8];
        #pragma unroll
        for (int q = 0; q < 8; ++q) wr[q] = *(const float4*)&sW0s[j * 32 + q * 4];
        #pragma unroll 2
        for (int k = 0; k < 16; ++k) {
            const int c = cg + k;
            v2f s0 = mkv2(0.f, 0.f), s1 = mkv2(0.f, 0.f);
            #pragma unroll
            for (int q = 0; q < 8; ++q) {
                const float4 t4 = *(const float4*)&sW1T[c * 32 + q * 4];
                s0 = pkfma(mkv2(t4.x, t4.y), mkv2(wr[q].x, wr[q].y), s0);
                s1 = pkfma(mkv2(t4.z, t4.w), mkv2(wr[q].z, wr[q].w), s1);
            }
            sM[j * 64 + c] = (s0.x + s1.x) + (s0.y + s1.y);
        }
    }
    __syncthreads();

    const int w    = tid >> 6;
    const int lane = tid & 63;
    const int bu   = __builtin_amdgcn_readfirstlane(blockIdx.x * 4 + w);
    const int m    = lane & 31;
    const int H    = lane & 32;          // half base (encoder only)
    const int rb   = lane & 48;          // 16-col quarter base in 64-space
    const int yq   = (lane & 48) >> 1;   // 8-col quarter base in 32-space

    float* __restrict__ xb = xbuf[w];
    float* __restrict__ hb = hbuf[w];

    // M quarter rows for rows {j, j^16, j^32, j^48} over cols [rb, rb+16)
    float WM0f[16], WM1f[16], WM2f[16], WM3f[16];
    #pragma unroll
    for (int q = 0; q < 4; ++q) {
        *(float4*)&WM0f[q * 4] = *(const float4*)&sM[lane * 64 + rb + q * 4];
        *(float4*)&WM1f[q * 4] = *(const float4*)&sM[(lane ^ 16) * 64 + rb + q * 4];
        *(float4*)&WM2f[q * 4] = *(const float4*)&sM[(lane ^ 32) * 64 + rb + q * 4];
        *(float4*)&WM3f[q * 4] = *(const float4*)&sM[(lane ^ 48) * 64 + rb + q * 4];
    }
    const v2f* WM0 = (const v2f*)WM0f; const v2f* WM1 = (const v2f*)WM1f;
    const v2f* WM2 = (const v2f*)WM2f; const v2f* WM3 = (const v2f*)WM3f;

    // W0y quarter rows for a1: rows {j, j^16, j^32, j^48} over y-cols [yq, yq+8)
    float W0Af[8], W0Bf[8], W0Cf[8], W0Df[8];
    #pragma unroll
    for (int q = 0; q < 2; ++q) {
        *(float4*)&W0Af[q * 4] = *(const float4*)&dynW0[lane * 48 + yq + q * 4];
        *(float4*)&W0Bf[q * 4] = *(const float4*)&dynW0[(lane ^ 16) * 48 + yq + q * 4];
        *(float4*)&W0Cf[q * 4] = *(const float4*)&dynW0[(lane ^ 32) * 48 + yq + q * 4];
        *(float4*)&W0Df[q * 4] = *(const float4*)&dynW0[(lane ^ 48) * 48 + yq + q * 4];
    }
    const v2f* W0A = (const v2f*)W0Af; const v2f* W0B = (const v2f*)W0Bf;
    const v2f* W0C = (const v2f*)W0Cf; const v2f* W0D = (const v2f*)W0Df;

    // W1 quarter rows for y-update: rows {m, m^16} over cols [rb, rb+16)
    float V10f[16], V11f[16];
    #pragma unroll
    for (int q = 0; q < 4; ++q) {
        *(float4*)&V10f[q * 4] = *(const float4*)&dynW1[m * 64 + rb + q * 4];
        *(float4*)&V11f[q * 4] = *(const float4*)&dynW1[(m ^ 16) * 64 + rb + q * 4];
    }
    const v2f* V10 = (const v2f*)V10f; const v2f* V11 = (const v2f*)V11f;

    // acl columns of W0 row j (full 16, row owned by this lane)
    float wa[16];
    #pragma unroll
    for (int q = 0; q < 4; ++q) *(float4*)&wa[q * 4] = *(const float4*)&dynW0[lane * 48 + 32 + q * 4];
    const float b0r = dynb0[lane];
    const float b1r = dynb1[m];

    // vj = W0y[lane,:] . b1  (transient full-row read)
    float vj = 0.f;
    #pragma unroll
    for (int q = 0; q < 8; ++q) {
        const float4 wv = *(const float4*)&dynW0[lane * 48 + q * 4];
        vj = fmaf(wv.x, sB1d[q * 4 + 0], vj); vj = fmaf(wv.y, sB1d[q * 4 + 1], vj);
        vj = fmaf(wv.z, sB1d[q * 4 + 2], vj); vj = fmaf(wv.w, sB1d[q * 4 + 3], vj);
    }

    tbuf[w][lane]      = times[bu * NT + lane];
    tbuf[w][64 + lane] = times[bu * NT + 64 + lane];
    __builtin_amdgcn_wave_barrier();

    // g_j = M[j,:].h + vj : quarter-dots + 3 cross-lane combines
    auto gproj = [&](float hsv, float vjv) -> float {
        __builtin_amdgcn_wave_barrier();
        hb[lane] = hsv;
        __builtin_amdgcn_wave_barrier();
        float hr[16];
        #pragma unroll
        for (int q = 0; q < 4; ++q) *(float4*)&hr[q * 4] = *(const float4*)&hb[rb + q * 4];
        const v2f* hp = (const v2f*)hr;
        v2f P0 = mkv2(0.f, 0.f), P1 = mkv2(0.f, 0.f);
        v2f P2 = mkv2(0.f, 0.f), P3 = mkv2(0.f, 0.f);
        #pragma unroll
        for (int q = 0; q < 8; ++q) {
            P0 = pkfma(hp[q], WM0[q], P0);
            P1 = pkfma(hp[q], WM1[q], P1);
            P2 = pkfma(hp[q], WM2[q], P2);
            P3 = pkfma(hp[q], WM3[q], P3);
        }
        const float p0 = P0.x + P0.y, p1 = P1.x + P1.y;
        const float p2 = P2.x + P2.y, p3 = P3.x + P3.y;
        const float u  = p0 + __shfl_xor(p1, 16, 64);
        const float vv = p2 + __shfl_xor(p3, 16, 64);
        return u + __shfl_xor(vv, 32, 64) + vjv;
    };

    // ---- encoder: ob(64) -> relu(64) -> y(32), y replicated in both halves
    float y;
    {
        xb[lane] = ob[bu * 64 + lane];
        __builtin_amdgcn_wave_barrier();
        float4 xv[16];
        #pragma unroll
        for (int q = 0; q < 16; ++q) xv[q] = *(const float4*)&xb[q * 4];
        float a0 = sEncB0[lane], a1 = 0.f, a2 = 0.f, a3 = 0.f;
        #pragma unroll
        for (int q = 0; q < 16; ++q) {
            a0 = fmaf(xv[q].x, sEncW0T[(q * 4 + 0) * 64 + lane], a0);
            a1 = fmaf(xv[q].y, sEncW0T[(q * 4 + 1) * 64 + lane], a1);
            a2 = fmaf(xv[q].z, sEncW0T[(q * 4 + 2) * 64 + lane], a2);
            a3 = fmaf(xv[q].w, sEncW0T[(q * 4 + 3) * 64 + lane], a3);
        }
        const float hj = fmaxf((a0 + a1) + (a2 + a3), 0.f);
        hb[lane] = hj;
        __builtin_amdgcn_wave_barrier();
        float4 hv[8];
        #pragma unroll
        for (int q = 0; q < 8; ++q) hv[q] = *(const float4*)&hb[H + q * 4];
        float c0 = 0.f, c1 = 0.f, c2 = 0.f, c3 = 0.f;
        #pragma unroll
        for (int q = 0; q < 8; ++q) {
            c0 = fmaf(hv[q].x, sEncW1T[(H + q * 4 + 0) * 32 + m], c0);
            c1 = fmaf(hv[q].y, sEncW1T[(H + q * 4 + 1) * 32 + m], c1);
            c2 = fmaf(hv[q].z, sEncW1T[(H + q * 4 + 2) * 32 + m], c2);
            c3 = fmaf(hv[q].w, sEncW1T[(H + q * 4 + 3) * 32 + m], c3);
        }
        float part = (c0 + c1) + (c2 + c3);
        part += __shfl_xor(part, 32, 64);
        y = part + sEncB1[m];
    }

    // per-lane acl partial: aclPart = sum_k w0[lane][32+k] * acl[k]
    auto acl_part = [&](const float* __restrict__ ap) -> float {
        float ar[16];
        #pragma unroll
        for (int q = 0; q < 4; ++q) *(float4*)&ar[q * 4] = *(const float4*)&ap[q * 4];
        const v2f* a2 = (const v2f*)ar;
        const v2f* wq = (const v2f*)wa;
        v2f s0 = mkv2(0.f, 0.f), s1 = mkv2(0.f, 0.f);
        #pragma unroll
        for (int q = 0; q < 8; q += 2) {
            s0 = pkfma(a2[q],     wq[q],     s0);
            s1 = pkfma(a2[q + 1], wq[q + 1], s1);
        }
        const v2f s = s0 + s1;
        return s.x + s.y;
    };

    auto store_y = [&](float yv, int t) {
        if (lane < 32) yio[(size_t)(bu * NT + t) * 64 + lane] = yv;
    };

    float aclPartC = acl_part(aclws + (size_t)(bu * NT) * 16);
    store_y(y, 0);

    for (int i = 0; i < NT - 1; ++i) {
        const float t0v = tbuf[w][i];
        const float t1v = tbuf[w][i + 1];
        const float hh  = (t1v - t0v) * 0.5f;                       // /K, K=2
        const float aclPartN = acl_part(aclws + (size_t)(bu * NT + i + 1) * 16);

        #pragma unroll 1
        for (int sub = 0; sub < 2; ++sub) {
            const float tsub  = t0v + (float)sub * hh;
            // stage-6 time fl(tsub+hh): matches reference searchsorted('right')
            const bool  swap6 = (tsub + hh >= t1v);

            // a1 = W0y*y + b0 + aclPartC : quarter-split x round trip
            __builtin_amdgcn_wave_barrier();
            xb[m] = y;                        // both pair-lanes: same addr, same data
            __builtin_amdgcn_wave_barrier();
            float a1v;
            {
                float xr[8];
                *(float4*)&xr[0] = *(const float4*)&xb[yq];
                *(float4*)&xr[4] = *(const float4*)&xb[yq + 4];
                const v2f* xp = (const v2f*)xr;
                v2f A0 = mkv2(0.f, 0.f), A1 = mkv2(0.f, 0.f);
                v2f A2 = mkv2(0.f, 0.f), A3 = mkv2(0.f, 0.f);
                #pragma unroll
                for (int q = 0; q < 4; ++q) {
                    A0 = pkfma(xp[q], W0A[q], A0);
                    A1 = pkfma(xp[q], W0B[q], A1);
                    A2 = pkfma(xp[q], W0C[q], A2);
                    A3 = pkfma(xp[q], W0D[q], A3);
                }
                const float q0 = A0.x + A0.y, q1 = A1.x + A1.y;
                const float q2 = A2.x + A2.y, q3 = A3.x + A3.y;
                const float u  = q0 + __shfl_xor(q1, 16, 64);
                const float vv = q2 + __shfl_xor(q3, 16, 64);
                a1v = u + __shfl_xor(vv, 32, 64) + b0r + aclPartC;
            }

            const float h1 = fmaxf(a1v, 0.f);
            const float g1 = hh * gproj(h1, vj);
            const float h2 = fmaxf(fmaf(0.2f, g1, a1v), 0.f);
            const float g2 = hh * gproj(h2, vj);
            const float h3 = fmaxf(fmaf(0.075f, g1, fmaf(0.225f, g2, a1v)), 0.f);
            const float g3 = hh * gproj(h3, vj);
            const float h4 = fmaxf(
                fmaf((float)(44.0/45.0), g1,
                fmaf((float)(-56.0/15.0), g2,
                fmaf((float)(32.0/9.0), g3, a1v))), 0.f);
            const float g4 = hh * gproj(h4, vj);
            const float h5 = fmaxf(
                fmaf((float)(19372.0/6561.0), g1,
                fmaf((float)(-25360.0/2187.0), g2,
                fmaf((float)(64448.0/6561.0), g3,
                fmaf((float)(-212.0/729.0), g4, a1v)))), 0.f);
            const float g5 = hh * gproj(h5, vj);
            float a6v =
                fmaf((float)(9017.0/3168.0), g1,
                fmaf((float)(-355.0/33.0), g2,
                fmaf((float)(46732.0/5247.0), g3,
                fmaf((float)(49.0/176.0), g4,
                fmaf((float)(-5103.0/18656.0), g5, a1v)))));
            a6v += swap6 ? (aclPartN - aclPartC) : 0.f;
            const float h6 = fmaxf(a6v, 0.f);

            // hacc = sum_s B_s h_s  (B2 = 0)
            float ha = (float)(35.0/384.0) * h1;
            ha = fmaf((float)(500.0/1113.0),   h3, ha);
            ha = fmaf((float)(125.0/192.0),    h4, ha);
            ha = fmaf((float)(-2187.0/6784.0), h5, ha);
            ha = fmaf((float)(11.0/84.0),      h6, ha);

            // y += hh*(W1*hacc + b1) : quarter-split hacc round trip
            __builtin_amdgcn_wave_barrier();
            hb[lane] = ha;
            __builtin_amdgcn_wave_barrier();
            {
                float hr[16];
                #pragma unroll
                for (int q = 0; q < 4; ++q) *(float4*)&hr[q * 4] = *(const float4*)&hb[rb + q * 4];
                const v2f* hp = (const v2f*)hr;
                v2f P0 = mkv2(0.f, 0.f), P1 = mkv2(0.f, 0.f);
                #pragma unroll
                for (int q = 0; q < 8; ++q) {
                    P0 = pkfma(hp[q], V10[q], P0);
                    P1 = pkfma(hp[q], V11[q], P1);
                }
                const float p0 = P0.x + P0.y, p1 = P1.x + P1.y;
                const float u  = p0 + __shfl_xor(p1, 16, 64);
                const float full = u + __shfl_xor(u, 32, 64);
                y = fmaf(hh, full + b1r, y);
            }
        }
        aclPartC = aclPartN;
        store_y(y, i + 1);
    }
}

// ---------------------------------------------------------------------------
// Kernel 3: decoder, one thread per (b,t) row, IN PLACE on out. Packed fp32.
// ---------------------------------------------------------------------------
__global__ __launch_bounds__(256, 2) void dec_kernel(
    const float* __restrict__ decW0, const float* __restrict__ decb0,
    const float* __restrict__ decW1, const float* __restrict__ decb1,
    float* __restrict__ yio)
{
    __shared__ float sW0[64 * 32];   // [j][k] as stored
    __shared__ float sW1T[64 * 64];  // [j][n]
    __shared__ float sB0[64];
    __shared__ float sB1[64];
    const int tid = threadIdx.x;
    for (int i = tid; i < 64 * 32; i += 256) sW0[i] = decW0[i];
    for (int i = tid; i < 64 * 64; i += 256) { int n = i >> 6, j = i & 63; sW1T[j * 64 + n] = decW1[i]; }
    if (tid < 64) { sB0[tid] = decb0[tid]; sB1[tid] = decb1[tid]; }
    __syncthreads();

    const size_t row = (size_t)blockIdx.x * 256 + tid;
    float* rp = &yio[row * 64];

    float xr[32];
    #pragma unroll
    for (int q = 0; q < 8; ++q) *(float4*)&xr[q * 4] = *(const float4*)&rp[q * 4];

    v2f o2[32];
    #pragma unroll
    for (int n = 0; n < 32; ++n) o2[n] = mkv2(sB1[2 * n], sB1[2 * n + 1]);

    #pragma unroll 4
    for (int j = 0; j < 64; ++j) {
        v2f a0 = mkv2(sB0[j], 0.f), a1 = mkv2(0.f, 0.f);
        #pragma unroll
        for (int q = 0; q < 8; ++q) {
            const float4 wv = *(const float4*)&sW0[j * 32 + q * 4];
            a0 = pkfma(*(const v2f*)&xr[q * 4],     mkv2(wv.x, wv.y), a0);
            a1 = pkfma(*(const v2f*)&xr[q * 4 + 2], mkv2(wv.z, wv.w), a1);
        }
        const float hj = fmaxf((a0.x + a1.x) + (a0.y + a1.y), 0.f);
        const v2f h2 = mkv2(hj, hj);
        #pragma unroll
        for (int q = 0; q < 16; ++q) {
            const float4 wv = *(const float4*)&sW1T[j * 64 + q * 4];
            o2[2 * q]     = pkfma(h2, mkv2(wv.x, wv.y), o2[2 * q]);
            o2[2 * q + 1] = pkfma(h2, mkv2(wv.z, wv.w), o2[2 * q + 1]);
        }
    }

    #pragma unroll
    for (int q = 0; q < 16; ++q)
        *(float4*)&rp[q * 4] = make_float4(o2[2 * q].x, o2[2 * q].y,
                                           o2[2 * q + 1].x, o2[2 * q + 1].y);
}

extern "C" void kernel_launch(void* const* d_in, const int* in_sizes, int n_in,
                              void* d_out, int out_size, void* d_ws, size_t ws_size,
                              hipStream_t stream)
{
    const float* encW0 = (const float*)d_in[0];
    const float* encb0 = (const float*)d_in[1];
    const float* encW1 = (const float*)d_in[2];
    const float* encb1 = (const float*)d_in[3];
    const float* acW0  = (const float*)d_in[4];
    const float* acb0  = (const float*)d_in[5];
    const float* acW1  = (const float*)d_in[6];
    const float* acb1  = (const float*)d_in[7];
    const float* dynW0 = (const float*)d_in[8];
    const float* dynb0 = (const float*)d_in[9];
    const float* dynW1 = (const float*)d_in[10];
    const float* dynb1 = (const float*)d_in[11];
    const float* decW0 = (const float*)d_in[12];
    const float* decb0 = (const float*)d_in[13];
    const float* decW1 = (const float*)d_in[14];
    const float* decb1 = (const float*)d_in[15];
    const float* ob    = (const float*)d_in[16];
    const float* acs   = (const float*)d_in[17];
    const float* times = (const float*)d_in[18];
    float* out = (float*)d_out;
    float* acl = (float*)d_ws;   // NB*NT*16 floats = 16.8 MB scratch

    acl_kernel<<<(NB * NT) / 256, 256, 0, stream>>>(acs, acW0, acb0, acW1, acb1, acl);
    ode_kernel<<<NB / 4, 256, 0, stream>>>(encW0, encb0, encW1, encb1,
                                           dynW0, dynb0, dynW1, dynb1,
                                           ob, times, acl, out);
    dec_kernel<<<(NB * NT) / 256, 256, 0, stream>>>(decW0, decb0, decW1, decb1, out);
}